// Round 1
// baseline (1108.532 us; speedup 1.0000x reference)
//
#include <hip/hip_runtime.h>

#define BN_EPS 1e-5f

constexpr int NB = 8, VWS = 4, TS = 5, VS = 17, CIN = 18, CH = 16;
constexpr int NODES = VWS * TS * VS;   // 340
constexpr int HW = 256;                // 16x16
constexpr int XSTR = 20;               // padded row stride for xs (16B-aligned rows)

__device__ __forceinline__ unsigned short f2bf(float f) {
    unsigned int u = __float_as_uint(f);
    u = u + 0x7fffu + ((u >> 16) & 1u);   // round-to-nearest-even
    return (unsigned short)(u >> 16);
}
__device__ __forceinline__ float bf2f(unsigned short s) {
    return __uint_as_float(((unsigned int)s) << 16);
}

__global__ __launch_bounds__(256, 2) void stgcn_fused(
    const float* __restrict__ x,
    const float* __restrict__ Asp_g, const float* __restrict__ Atm_g, const float* __restrict__ Avw_g,
    const float* __restrict__ Wg0, const float* __restrict__ bg0,
    const float* __restrict__ Wgx, const float* __restrict__ bgx,
    const float* __restrict__ g1, const float* __restrict__ b1,
    const float* __restrict__ Wt, const float* __restrict__ bt,
    const float* __restrict__ g2, const float* __restrict__ b2,
    float* __restrict__ out)
{
    __shared__ __align__(16) float xs[NODES * XSTR];           // 27200 B (fp32, holds layer input)
    __shared__ __align__(16) unsigned short z1s[NODES * 16];   // 10880 B (bf16 conv1 out)
    __shared__ __align__(16) unsigned short z2s[NODES * 16];   // 10880 B (bf16 aggregated/relu)
    __shared__ __align__(16) float acc[NODES * 16];            // 21760 B (fp32 branch accumulator)
    __shared__ float Asp[4 * 17 * 17];                         // 4624 B
    __shared__ float Atm[2 * 5 * 5];                           // 200 B
    __shared__ float Avw[16];                                  // 64 B

    const int tid = threadIdx.x;
    const int o = tid & 15;    // output channel owned by this thread
    const int r = tid >> 4;    // node-row slot (0..15)
    const int site = blockIdx.x;
    const int n = site >> 8;
    const int hw = site & 255;

    // stage adjacency matrices
    for (int i = tid; i < 4 * 17 * 17; i += 256) Asp[i] = Asp_g[i];
    if (tid < 50) Atm[tid] = Atm_g[tid];
    if (tid < 16) Avw[tid] = Avw_g[tid];

    // load this site's tensor: x[(n*340+node)*18 + c][hw]
    const float* xb = x + (size_t)n * NODES * CIN * HW + hw;
    for (int i = tid; i < NODES * CIN; i += 256) {
        int node = i / CIN, c = i - node * CIN;
        xs[node * XSTR + c] = xb[(size_t)i * HW];
    }
    __syncthreads();

    const float rs = 1.0f / sqrtf(1.0f + BN_EPS);

    for (int l = 0; l < 3; ++l) {
        // --- init accumulator: residual = 7*x for layers 1,2 (each of 7 branches adds x) ---
        if (l == 0) {
            for (int p = r; p < NODES; p += 16) acc[p * 16 + o] = 0.f;
        } else {
            for (int p = r; p < NODES; p += 16) acc[p * 16 + o] = 7.f * xs[p * XSTR + o];
        }

        for (int k = 0; k < 7; ++k) {
            const int lk = l * 7 + k;

            // --- fold bn1 scale into conv1 weights (per-thread, o fixed) ---
            float wgr[CIN];
            const float s1v = g1[lk * 16 + o] * rs;
            const float b1v = b1[lk * 16 + o];
            float bgv;
            if (l == 0) {
                const float* wp = Wg0 + (k * 16 + o) * CIN;
                #pragma unroll
                for (int c = 0; c < CIN; ++c) wgr[c] = wp[c] * s1v;
                bgv = bg0[k * 16 + o] * s1v;
            } else {
                const float* wp = Wgx + (((l - 1) * 7 + k) * 16 + o) * 16;
                #pragma unroll
                for (int c = 0; c < 16; ++c) wgr[c] = wp[c] * s1v;
                wgr[16] = 0.f; wgr[17] = 0.f;
                bgv = bgx[((l - 1) * 7 + k) * 16 + o] * s1v;
            }

            // --- conv1: z1[p][o] = s1*(Wg x[p] + bg) ---
            for (int p = r; p < NODES; p += 16) {
                const float4* xr = (const float4*)&xs[p * XSTR];
                float4 a0 = xr[0], a1 = xr[1], a2 = xr[2], a3 = xr[3];
                float sA = bgv, sB = 0.f;
                sA = fmaf(wgr[0],  a0.x, sA); sB = fmaf(wgr[1],  a0.y, sB);
                sA = fmaf(wgr[2],  a0.z, sA); sB = fmaf(wgr[3],  a0.w, sB);
                sA = fmaf(wgr[4],  a1.x, sA); sB = fmaf(wgr[5],  a1.y, sB);
                sA = fmaf(wgr[6],  a1.z, sA); sB = fmaf(wgr[7],  a1.w, sB);
                sA = fmaf(wgr[8],  a2.x, sA); sB = fmaf(wgr[9],  a2.y, sB);
                sA = fmaf(wgr[10], a2.z, sA); sB = fmaf(wgr[11], a2.w, sB);
                sA = fmaf(wgr[12], a3.x, sA); sB = fmaf(wgr[13], a3.y, sB);
                sA = fmaf(wgr[14], a3.z, sA); sB = fmaf(wgr[15], a3.w, sB);
                if (l == 0) {
                    sA = fmaf(wgr[16], xs[p * XSTR + 16], sA);
                    sB = fmaf(wgr[17], xs[p * XSTR + 17], sB);
                }
                z1s[p * 16 + o] = f2bf(sA + sB);
            }
            __syncthreads();

            // --- aggregation over the k-specific graph axis, + b1, relu ---
            for (int p = r; p < NODES; p += 16) {
                float sA = b1v;
                if (k < 4) {                       // mix over V (17), groups = (vw,t)
                    int grp = p / 17, u = p - grp * 17;
                    const float* Ar = &Asp[(k * 17 + u) * 17];
                    const int base = grp * (17 * 16) + o;
                    float sB = 0.f;
                    #pragma unroll
                    for (int v = 0; v < 17; ++v) {
                        float val = bf2f(z1s[base + v * 16]);
                        if (v & 1) sB = fmaf(Ar[v], val, sB);
                        else       sA = fmaf(Ar[v], val, sA);
                    }
                    sA += sB;
                } else if (k < 6) {                // mix over T (5), groups = (vw,v)
                    int vw = p / 85, rm = p - vw * 85;
                    int tq = rm / 17, v = rm - tq * 17;
                    const float* Ar = &Atm[((k - 4) * 5 + tq) * 5];
                    const int base = (vw * 85 + v) * 16 + o;
                    #pragma unroll
                    for (int tt = 0; tt < 5; ++tt)
                        sA = fmaf(Ar[tt], bf2f(z1s[base + tt * (17 * 16)]), sA);
                } else {                           // mix over VIEWS (4), groups = (t,v)
                    int vw = p / 85, tv = p - vw * 85;
                    const float* Ar = &Avw[vw * 4];
                    const int base = tv * 16 + o;
                    #pragma unroll
                    for (int w2 = 0; w2 < 4; ++w2)
                        sA = fmaf(Ar[w2], bf2f(z1s[base + w2 * (85 * 16)]), sA);
                }
                z2s[p * 16 + o] = f2bf(fmaxf(sA, 0.f));
            }
            __syncthreads();

            // --- conv2 (+ folded bn2), accumulate into acc ---
            float wtr[16];
            const float s2v = g2[lk * 16 + o] * rs;
            const float* wp2 = Wt + (lk * 16 + o) * 16;
            #pragma unroll
            for (int c = 0; c < 16; ++c) wtr[c] = wp2[c] * s2v;
            const float btv = fmaf(bt[lk * 16 + o], s2v, b2[lk * 16 + o]);

            for (int p = r; p < NODES; p += 16) {
                const uint4* zr = (const uint4*)&z2s[p * 16];
                uint4 q0 = zr[0], q1 = zr[1];
                float sA = btv, sB = 0.f;
                sA = fmaf(wtr[0],  __uint_as_float(q0.x << 16), sA);
                sB = fmaf(wtr[1],  __uint_as_float(q0.x & 0xffff0000u), sB);
                sA = fmaf(wtr[2],  __uint_as_float(q0.y << 16), sA);
                sB = fmaf(wtr[3],  __uint_as_float(q0.y & 0xffff0000u), sB);
                sA = fmaf(wtr[4],  __uint_as_float(q0.z << 16), sA);
                sB = fmaf(wtr[5],  __uint_as_float(q0.z & 0xffff0000u), sB);
                sA = fmaf(wtr[6],  __uint_as_float(q0.w << 16), sA);
                sB = fmaf(wtr[7],  __uint_as_float(q0.w & 0xffff0000u), sB);
                sA = fmaf(wtr[8],  __uint_as_float(q1.x << 16), sA);
                sB = fmaf(wtr[9],  __uint_as_float(q1.x & 0xffff0000u), sB);
                sA = fmaf(wtr[10], __uint_as_float(q1.y << 16), sA);
                sB = fmaf(wtr[11], __uint_as_float(q1.y & 0xffff0000u), sB);
                sA = fmaf(wtr[12], __uint_as_float(q1.z << 16), sA);
                sB = fmaf(wtr[13], __uint_as_float(q1.z & 0xffff0000u), sB);
                sA = fmaf(wtr[14], __uint_as_float(q1.w << 16), sA);
                sB = fmaf(wtr[15], __uint_as_float(q1.w & 0xffff0000u), sB);
                acc[p * 16 + o] += sA + sB;
            }
            // no barrier needed here: next conv1 writes z1 (safe), and the barrier
            // after it orders these z2 reads before the next aggregation's z2 writes.
        }

        // --- finalize layer: relu(acc) -> new x (or output) ---
        if (l < 2) {
            for (int p = r; p < NODES; p += 16)
                xs[p * XSTR + o] = fmaxf(acc[p * 16 + o], 0.f);
            __syncthreads();
        } else {
            float* ob = out + (size_t)n * NODES * 16 * HW + hw;
            for (int p = r; p < NODES; p += 16)
                ob[(size_t)(p * 16 + o) * HW] = fmaxf(acc[p * 16 + o], 0.f);
        }
    }
}

extern "C" void kernel_launch(void* const* d_in, const int* in_sizes, int n_in,
                              void* d_out, int out_size, void* d_ws, size_t ws_size,
                              hipStream_t stream) {
    const float* x    = (const float*)d_in[0];
    const float* Asp  = (const float*)d_in[1];
    const float* Atm  = (const float*)d_in[2];
    const float* Avw  = (const float*)d_in[3];
    const float* Wg0  = (const float*)d_in[4];
    const float* bg0  = (const float*)d_in[5];
    const float* Wgx  = (const float*)d_in[6];
    const float* bgx  = (const float*)d_in[7];
    const float* g1   = (const float*)d_in[8];
    const float* b1   = (const float*)d_in[9];
    const float* Wt   = (const float*)d_in[10];
    const float* bt   = (const float*)d_in[11];
    const float* g2   = (const float*)d_in[12];
    const float* b2   = (const float*)d_in[13];
    float* out = (float*)d_out;

    stgcn_fused<<<dim3(NB * HW), dim3(256), 0, stream>>>(
        x, Asp, Atm, Avw, Wg0, bg0, Wgx, bgx, g1, b1, Wt, bt, g2, b2, out);
}

// Round 2
// 777.089 us; speedup vs baseline: 1.4265x; 1.4265x over previous
//
#include <hip/hip_runtime.h>

typedef __attribute__((ext_vector_type(8))) short bf16x8;   // 8 bf16 (4 VGPRs)
typedef __attribute__((ext_vector_type(4))) float f32x4;

constexpr int NODESV = 340;     // valid nodes = 4*5*17
constexpr int CIN = 18;
constexpr int NSLOT = 480;      // 20 groups * 24 padded slots
constexpr int NTILE = 30;       // 480/16
constexpr int RS1 = 488;        // z1g row stride (elems): 480 + 8 overreach
constexpr int SL8 = NSLOT * 8;  // 3840: slice stride for [slice][slot][8] layouts

__device__ __forceinline__ unsigned short f2bf(float f) {
    unsigned int u = __float_as_uint(f);
    u = u + 0x7fffu + ((u >> 16) & 1u);   // RNE
    return (unsigned short)(u >> 16);
}
__device__ __forceinline__ float bf2f(unsigned short s) {
    return __uint_as_float(((unsigned int)s) << 16);
}
__device__ __forceinline__ unsigned pack2(unsigned short a, unsigned short b) {
    return (unsigned)a | ((unsigned)b << 16);
}

__global__ __launch_bounds__(256, 2) void stgcn_mfma(
    const float* __restrict__ x,
    const float* __restrict__ Asp_g, const float* __restrict__ Atm_g, const float* __restrict__ Avw_g,
    const float* __restrict__ Wg0, const float* __restrict__ bg0,
    const float* __restrict__ Wgx, const float* __restrict__ bgx,
    const float* __restrict__ g1, const float* __restrict__ b1,
    const float* __restrict__ Wt, const float* __restrict__ bt,
    const float* __restrict__ g2, const float* __restrict__ b2,
    float* __restrict__ out)
{
    // [slice][slot][8] bf16 subtiled layouts -> aligned ds_read_b128 MFMA frags
    __shared__ __align__(16) unsigned short xsb[3 * SL8];   // x: c0-7, c8-15, c16-23  (23040 B)
    __shared__ __align__(16) unsigned short z1g[16 * RS1];  // z1 transposed [o][slot] (15616 B)
    __shared__ __align__(16) unsigned short z2s[2 * SL8];   // z2: c0-7, c8-15         (15360 B)
    __shared__ float Atm_s[50];
    __shared__ float Avw_s[16];

    const int tid  = threadIdx.x;
    const int wv   = tid >> 6;          // wave 0..3
    const int o    = tid & 15;          // MFMA row/col index & channel
    const int quad = (tid >> 4) & 3;    // lane>>4 within wave
    const int bid  = blockIdx.x;
    const int n  = bid & 7;             // XCD swizzle: one batch image per XCD
    const int hw = bid >> 3;

    // ---- zero LDS (pads must be finite-zero), stage small A matrices ----
    for (int i = tid; i < 3 * SL8 / 2; i += 256) ((unsigned*)xsb)[i] = 0u;
    for (int i = tid; i < 16 * RS1 / 2; i += 256) ((unsigned*)z1g)[i] = 0u;
    for (int i = tid; i < 2 * SL8 / 2; i += 256) ((unsigned*)z2s)[i] = 0u;
    if (tid < 50) Atm_s[tid] = Atm_g[tid];
    if (tid < 16) Avw_s[tid] = Avw_g[tid];
    __syncthreads();

    // ---- load this site's x -> bf16 LDS ----
    const float* xb = x + (size_t)n * NODESV * CIN * 256 + hw;
    for (int i = tid; i < NODESV * CIN; i += 256) {
        int p = i / CIN, c = i - p * CIN;
        int slot = p + 7 * (p / 17);          // group-padded slot
        float v = xb[(size_t)i * 256];
        int idx = (c < 16) ? ((c >> 3) * SL8 + slot * 8 + (c & 7))
                           : (2 * SL8 + slot * 8 + (c - 16));
        xsb[idx] = f2bf(v);
    }

    // ---- build adjacency MFMA A-frags (bf16, registers, reused all layers) ----
    bf16x8 aspA[4], aspB[4];
    #pragma unroll
    for (int kk = 0; kk < 4; ++kk) {
        bf16x8 a0 = {}, a1 = {};
        #pragma unroll
        for (int i = 0; i < 8; ++i) {
            int v = quad * 8 + i;
            float f0 = (v < 17) ? Asp_g[(kk * 17 + o) * 17 + v] : 0.f;
            float f1 = (o == 0 && v < 17) ? Asp_g[(kk * 17 + 16) * 17 + v] : 0.f;
            a0[i] = (short)f2bf(f0);
            a1[i] = (short)f2bf(f1);
        }
        aspA[kk] = a0; aspB[kk] = a1;
    }
    __syncthreads();

    const float rs = 1.0f / sqrtf(1.0f + 1e-5f);
    f32x4 acc[8], res8[8];

    for (int l = 0; l < 3; ++l) {
        float Sb = 0.f;
        #pragma unroll
        for (int t = 0; t < 8; ++t) {
            f32x4 z = {0.f, 0.f, 0.f, 0.f};
            acc[t] = (l == 0) ? z : 7.f * res8[t];
        }

        for (int k = 0; k < 7; ++k) {
            const int lk = l * 7 + k;
            const float s1v = g1[lk * 16 + o] * rs;
            const float b1v = b1[lk * 16 + o];
            const float s2v = g2[lk * 16 + o] * rs;
            Sb += bt[lk * 16 + o] * s2v + b2[lk * 16 + o];

            // conv1 weight frag (bn1 scale folded), B[k=c][col=o]
            bf16x8 wg = {};
            float bgv;
            if (l == 0) {
                const float* wr = Wg0 + (k * 16 + o) * 18;
                #pragma unroll
                for (int i = 0; i < 8; ++i) {
                    int c = quad * 8 + i;
                    wg[i] = (c < 18) ? (short)f2bf(wr[c] * s1v) : (short)0;
                }
                bgv = bg0[k * 16 + o] * s1v;
            } else {
                const float* wr = Wgx + (((l - 1) * 7 + k) * 16 + o) * 16;
                #pragma unroll
                for (int i = 0; i < 8; ++i) {
                    int c = quad * 8 + i;
                    wg[i] = (c < 16) ? (short)f2bf(wr[c] * s1v) : (short)0;
                }
                bgv = bgx[((l - 1) * 7 + k) * 16 + o] * s1v;
            }
            // conv2 weight frag (bn2 scale folded)
            bf16x8 wt = {};
            {
                const float* wr2 = Wt + (lk * 16 + o) * 16;
                #pragma unroll
                for (int i = 0; i < 8; ++i) {
                    int c = quad * 8 + i;
                    wt[i] = (c < 16) ? (short)f2bf(wr2[c] * s2v) : (short)0;
                }
            }

            // ---- conv1: z1[slot][o] = s1*(Wg x + bg) via MFMA ----
            #pragma unroll
            for (int t = 0; t < 8; ++t) {
                int tile = t * 4 + wv;
                if (tile < NTILE) {
                    int node = tile * 16 + o;
                    int cs = (l == 0) ? (quad == 3 ? 0 : quad) : (quad & 1);
                    bf16x8 xa = *(const bf16x8*)&xsb[cs * SL8 + node * 8];
                    f32x4 z = {0.f, 0.f, 0.f, 0.f};
                    z = __builtin_amdgcn_mfma_f32_16x16x32_bf16(xa, wg, z, 0, 0, 0);
                    int n0 = tile * 16 + quad * 4;
                    unsigned w0 = pack2(f2bf(z[0] + bgv), f2bf(z[1] + bgv));
                    unsigned w1 = pack2(f2bf(z[2] + bgv), f2bf(z[3] + bgv));
                    *(uint2*)&z1g[o * RS1 + n0] = make_uint2(w0, w1);
                }
            }
            __syncthreads();

            // ---- aggregation ----
            if (k < 4) {            // V-mix per (vw,t) group: MFMA, A=A_sp
                #pragma unroll
                for (int gi = 0; gi < 5; ++gi) {
                    int grp = gi * 4 + wv;
                    bf16x8 bz = *(const bf16x8*)&z1g[o * RS1 + grp * 24 + quad * 8];
                    f32x4 y0 = {0.f, 0.f, 0.f, 0.f};
                    f32x4 y1 = {0.f, 0.f, 0.f, 0.f};
                    y0 = __builtin_amdgcn_mfma_f32_16x16x32_bf16(aspA[k], bz, y0, 0, 0, 0);
                    y1 = __builtin_amdgcn_mfma_f32_16x16x32_bf16(aspB[k], bz, y1, 0, 0, 0);
                    int s0 = grp * 24 + quad * 4;
                    #pragma unroll
                    for (int j = 0; j < 4; ++j) {
                        float yv = fmaxf(y0[j] + b1v, 0.f);
                        z2s[(o >> 3) * SL8 + (s0 + j) * 8 + (o & 7)] = f2bf(yv);
                    }
                    if (quad == 0) {   // u = 16 row from tile2
                        float yv = fmaxf(y1[0] + b1v, 0.f);
                        z2s[(o >> 3) * SL8 + (grp * 24 + 16) * 8 + (o & 7)] = f2bf(yv);
                    }
                }
            } else if (k < 6) {     // T-mix (K=5): VALU
                const float* Ar = Atm_s + (k - 4) * 25;
                const int u = tid >> 4;
                for (int p = u; p < NODESV; p += 16) {
                    int q = p / 17, v = p - q * 17;
                    int vw2 = q / 5, tt = q - vw2 * 5;
                    float y = b1v;
                    #pragma unroll
                    for (int t2 = 0; t2 < 5; ++t2)
                        y = fmaf(Ar[tt * 5 + t2], bf2f(z1g[o * RS1 + vw2 * 120 + t2 * 24 + v]), y);
                    int slot = q * 24 + v;
                    z2s[(o >> 3) * SL8 + slot * 8 + (o & 7)] = f2bf(fmaxf(y, 0.f));
                }
            } else {                // View-mix (K=4): VALU
                const int u = tid >> 4;
                for (int p = u; p < NODESV; p += 16) {
                    int q = p / 17, v = p - q * 17;
                    int vw2 = q / 5, tt = q - vw2 * 5;
                    float y = b1v;
                    #pragma unroll
                    for (int w2 = 0; w2 < 4; ++w2)
                        y = fmaf(Avw_s[vw2 * 4 + w2], bf2f(z1g[o * RS1 + w2 * 120 + tt * 24 + v]), y);
                    int slot = q * 24 + v;
                    z2s[(o >> 3) * SL8 + slot * 8 + (o & 7)] = f2bf(fmaxf(y, 0.f));
                }
            }
            __syncthreads();

            // ---- conv2: acc += Wt' z2 (MFMA accumulates across branches) ----
            #pragma unroll
            for (int t = 0; t < 8; ++t) {
                int tile = t * 4 + wv;
                if (tile < NTILE) {
                    int node = tile * 16 + o;
                    bf16x8 za = *(const bf16x8*)&z2s[(quad & 1) * SL8 + node * 8];
                    acc[t] = __builtin_amdgcn_mfma_f32_16x16x32_bf16(za, wt, acc[t], 0, 0, 0);
                }
            }
            // no barrier needed: next conv1 touches z1g only; z2s rewritten after next barrier
        }

        // ---- finalize layer: relu(acc + Sb) -> res regs + xsb, or output ----
        #pragma unroll
        for (int t = 0; t < 8; ++t) {
            int tile = t * 4 + wv;
            if (tile < NTILE) {
                int s0 = tile * 16 + quad * 4;
                #pragma unroll
                for (int j = 0; j < 4; ++j) {
                    float val = fmaxf(acc[t][j] + Sb, 0.f);
                    if (l < 2) {
                        res8[t][j] = val;
                        xsb[(o >> 3) * SL8 + (s0 + j) * 8 + (o & 7)] = f2bf(val);
                    } else {
                        int slot = s0 + j;
                        int m = slot / 24, v = slot - 24 * m;
                        if (v < 17) {
                            int p = m * 17 + v;
                            out[((size_t)((n * NODESV + p) * 16 + o)) * 256 + hw] = val;
                        }
                    }
                }
            }
        }
        if (l < 2) __syncthreads();
    }
}

extern "C" void kernel_launch(void* const* d_in, const int* in_sizes, int n_in,
                              void* d_out, int out_size, void* d_ws, size_t ws_size,
                              hipStream_t stream) {
    const float* x    = (const float*)d_in[0];
    const float* Asp  = (const float*)d_in[1];
    const float* Atm  = (const float*)d_in[2];
    const float* Avw  = (const float*)d_in[3];
    const float* Wg0  = (const float*)d_in[4];
    const float* bg0  = (const float*)d_in[5];
    const float* Wgx  = (const float*)d_in[6];
    const float* bgx  = (const float*)d_in[7];
    const float* g1   = (const float*)d_in[8];
    const float* b1   = (const float*)d_in[9];
    const float* Wt   = (const float*)d_in[10];
    const float* bt   = (const float*)d_in[11];
    const float* g2   = (const float*)d_in[12];
    const float* b2   = (const float*)d_in[13];
    float* out = (float*)d_out;

    stgcn_mfma<<<dim3(8 * 256), dim3(256), 0, stream>>>(
        x, Asp, Atm, Avw, Wg0, bg0, Wgx, bgx, g1, b1, Wt, bt, g2, b2, out);
}

// Round 3
// 687.530 us; speedup vs baseline: 1.6123x; 1.1303x over previous
//
#include <hip/hip_runtime.h>
#include <hip/hip_bf16.h>

typedef __attribute__((ext_vector_type(8))) short bf16x8;
typedef __attribute__((ext_vector_type(4))) float f32x4;
typedef unsigned short ush;

constexpr int NODESV = 340, CIN = 18;
constexpr int NTILE = 30, RS1 = 488;
constexpr int SLX = 3848;   // xsb slice stride (elems), bank-staggered
constexpr int SL8 = 3840;   // z2s slice stride

// d_ws layout (bytes)
constexpr int WS_SB_F = 21 * 16;                 // SbA float offset after bgvA
constexpr int WS_WG = 1536;                      // bf16 frags [21][64][8]
constexpr int WS_WT = WS_WG + 21 * 64 * 8 * 2;   // + 21504

__device__ __forceinline__ ush f2bf(float f) {
    union { __hip_bfloat16 h; ush u; } c; c.h = __float2bfloat16(f); return c.u;
}
__device__ __forceinline__ float bf2f(ush s) {
    return __uint_as_float((unsigned)s << 16);
}
__device__ __forceinline__ unsigned pkbf2(float lo, float hi) {
    union { __hip_bfloat162 h; unsigned u; } c;
    c.h = __float22bfloat162_rn(make_float2(lo, hi));
    return c.u;
}

// ---------------- prep: fold BN into bf16 weight frags, once ----------------
__global__ void stgcn_prep(
    const float* __restrict__ Wg0, const float* __restrict__ bg0,
    const float* __restrict__ Wgx, const float* __restrict__ bgx,
    const float* __restrict__ g1,  const float* __restrict__ b1,
    const float* __restrict__ Wt,  const float* __restrict__ bt,
    const float* __restrict__ g2,  const float* __restrict__ b2,
    void* __restrict__ ws)
{
    const int lk = blockIdx.x;            // 0..20
    const int l = lk / 7, k = lk % 7;
    const int lane = threadIdx.x;         // 0..63
    const int o = lane & 15, quad = lane >> 4;
    float* bgvA = (float*)ws;
    float* SbA  = bgvA + WS_SB_F;
    ush* wgF = (ush*)((char*)ws + WS_WG);
    ush* wtF = (ush*)((char*)ws + WS_WT);
    const float rs = 1.0f / sqrtf(1.0f + 1e-5f);
    const float s1 = g1[lk * 16 + o] * rs;
    const float s2 = g2[lk * 16 + o] * rs;

    unsigned wg4[4], wt4[4];
    #pragma unroll
    for (int i2 = 0; i2 < 4; ++i2) {
        int c0 = quad * 8 + i2 * 2, c1 = c0 + 1;
        float a0, a1;
        if (l == 0) {
            a0 = (c0 < 18) ? Wg0[(k * 16 + o) * 18 + c0] * s1 : 0.f;
            a1 = (c1 < 18) ? Wg0[(k * 16 + o) * 18 + c1] * s1 : 0.f;
        } else {
            a0 = (c0 < 16) ? Wgx[(((l - 1) * 7 + k) * 16 + o) * 16 + c0] * s1 : 0.f;
            a1 = (c1 < 16) ? Wgx[(((l - 1) * 7 + k) * 16 + o) * 16 + c1] * s1 : 0.f;
        }
        float t0 = (c0 < 16) ? Wt[(lk * 16 + o) * 16 + c0] * s2 : 0.f;
        float t1 = (c1 < 16) ? Wt[(lk * 16 + o) * 16 + c1] * s2 : 0.f;
        wg4[i2] = pkbf2(a0, a1);
        wt4[i2] = pkbf2(t0, t1);
    }
    *(uint4*)&wgF[(lk * 64 + lane) * 8] = make_uint4(wg4[0], wg4[1], wg4[2], wg4[3]);
    *(uint4*)&wtF[(lk * 64 + lane) * 8] = make_uint4(wt4[0], wt4[1], wt4[2], wt4[3]);
    if (quad == 0)
        bgvA[lk * 16 + o] = ((l == 0) ? bg0[k * 16 + o] : bgx[((l - 1) * 7 + k) * 16 + o]) * s1;
    if (lk == 0 && lane < 48) {
        int ll = lane >> 4, ch = lane & 15;
        float s = 0.f;
        for (int kk = 0; kk < 7; ++kk) {
            int q = (ll * 7 + kk) * 16 + ch;
            s += bt[q] * (g2[q] * rs) + b2[q];
        }
        SbA[ll * 16 + ch] = s;
    }
}

// ---------------- main fused 3-layer kernel, one block per (n,hw) ----------------
__global__ __launch_bounds__(256, 3) void stgcn_main(
    const float* __restrict__ x,
    const float* __restrict__ Asp_g, const float* __restrict__ Atm_g, const float* __restrict__ Avw_g,
    const float* __restrict__ b1, const void* __restrict__ ws,
    float* __restrict__ out)
{
    __shared__ __align__(16) ush xsb[3 * SLX];   // 23088 B
    __shared__ __align__(16) ush z1g[16 * RS1];  // 15616 B  [o][slot] bf16
    __shared__ __align__(16) ush z2s[2 * SL8];   // 15360 B  [c>>3][slot][c&7]

    const int tid  = threadIdx.x;
    const int wv   = tid >> 6;
    const int lane = tid & 63;
    const int o    = tid & 15;
    const int quad = (tid >> 4) & 3;
    const int w16  = tid >> 4;       // 0..15 (T/V mixes)
    const int bid  = blockIdx.x;
    const int n = bid & 7, hw = bid >> 3;   // XCD swizzle

    const float* bgvA = (const float*)ws;
    const float* SbA  = bgvA + WS_SB_F;
    const ush* wgF = (const ush*)((const char*)ws + WS_WG);
    const ush* wtF = (const ush*)((const char*)ws + WS_WT);

    // zero LDS (pads/tails must be finite-zero)
    for (int i = tid; i < (3 * SLX) / 2; i += 256) ((unsigned*)xsb)[i] = 0u;
    for (int i = tid; i < (16 * RS1) / 2; i += 256) ((unsigned*)z1g)[i] = 0u;
    for (int i = tid; i < (2 * SL8) / 2; i += 256) ((unsigned*)z2s)[i] = 0u;
    __syncthreads();

    // load x -> bf16 LDS
    const float* xb = x + (size_t)n * NODESV * CIN * 256 + hw;
    for (int i = tid; i < NODESV * CIN; i += 256) {
        int p = i / CIN, c = i - p * CIN;
        int slot = p + 7 * (p / 17);
        float v = xb[(size_t)i * 256];
        int idx = (c < 16) ? ((c >> 3) * SLX + slot * 8 + (c & 7))
                           : (2 * SLX + slot * 8 + (c - 16));
        xsb[idx] = f2bf(v);
    }

    // adjacency frags (valid as A- or B-operand: value = Asp[u=lane&15, v=quad*8+i])
    bf16x8 aspA[4], aspB[4];
    #pragma unroll
    for (int kk = 0; kk < 4; ++kk) {
        bf16x8 a0 = {}, a1 = {};
        #pragma unroll
        for (int i = 0; i < 8; ++i) {
            int v = quad * 8 + i;
            a0[i] = (short)((v < 17) ? f2bf(Asp_g[(kk * 17 + o) * 17 + v]) : 0);
            a1[i] = (short)((o == 0 && v < 17) ? f2bf(Asp_g[(kk * 17 + 16) * 17 + v]) : 0);
        }
        aspA[kk] = a0; aspB[kk] = a1;
    }
    __syncthreads();

    f32x4 acc[8], res8[8];

    for (int l = 0; l < 3; ++l) {
        #pragma unroll
        for (int t = 0; t < 8; ++t) {
            if (l == 0) { f32x4 z = {0.f, 0.f, 0.f, 0.f}; acc[t] = z; }
            else        acc[t] = 7.f * res8[t];
        }

        for (int k = 0; k < 7; ++k) {
            const int lk = l * 7 + k;
            bf16x8 wg = *(const bf16x8*)&wgF[(lk * 64 + lane) * 8];
            bf16x8 wt = *(const bf16x8*)&wtF[(lk * 64 + lane) * 8];
            const float bgv = bgvA[lk * 16 + o];

            // ---- conv1: z1[o][slot] via MFMA (bias in C-operand) ----
            const int cs = (l == 0) ? ((quad == 3) ? 0 : quad) : (quad & 1);
            #pragma unroll
            for (int t = 0; t < 8; ++t) {
                int tile = t * 4 + wv;
                if (tile < NTILE) {
                    int node = tile * 16 + o;
                    bf16x8 xa = *(const bf16x8*)&xsb[cs * SLX + node * 8];
                    f32x4 z = {bgv, bgv, bgv, bgv};
                    z = __builtin_amdgcn_mfma_f32_16x16x32_bf16(xa, wg, z, 0, 0, 0);
                    *(uint2*)&z1g[o * RS1 + tile * 16 + quad * 4] =
                        make_uint2(pkbf2(z[0], z[1]), pkbf2(z[2], z[3]));
                }
            }
            __syncthreads();

            // ---- aggregation -> z2s [c>>3][slot][c&7] ----
            if (k < 4) {   // V-mix, transposed MFMA: lane holds 4 channels of node u=o
                float4 b1q = *(const float4*)&b1[lk * 16 + quad * 4];
                #pragma unroll
                for (int gi = 0; gi < 5; ++gi) {
                    int grp = gi * 4 + wv;
                    bf16x8 bz = *(const bf16x8*)&z1g[o * RS1 + grp * 24 + quad * 8];
                    f32x4 y0 = {b1q.x, b1q.y, b1q.z, b1q.w};
                    y0 = __builtin_amdgcn_mfma_f32_16x16x32_bf16(bz, aspA[k], y0, 0, 0, 0);
                    f32x4 y1 = {b1q.x, b1q.y, b1q.z, b1q.w};
                    y1 = __builtin_amdgcn_mfma_f32_16x16x32_bf16(bz, aspB[k], y1, 0, 0, 0);
                    *(uint2*)&z2s[(quad >> 1) * SL8 + (grp * 24 + o) * 8 + (quad & 1) * 4] =
                        make_uint2(pkbf2(fmaxf(y0[0], 0.f), fmaxf(y0[1], 0.f)),
                                   pkbf2(fmaxf(y0[2], 0.f), fmaxf(y0[3], 0.f)));
                    if (o == 0) {   // node u=16 of the group
                        *(uint2*)&z2s[(quad >> 1) * SL8 + (grp * 24 + 16) * 8 + (quad & 1) * 4] =
                            make_uint2(pkbf2(fmaxf(y1[0], 0.f), fmaxf(y1[1], 0.f)),
                                       pkbf2(fmaxf(y1[2], 0.f), fmaxf(y1[3], 0.f)));
                    }
                }
            } else if (k < 6) {   // T-mix (K=5), per-group VALU
                const float b1v = b1[lk * 16 + o];
                const float* Ar = Atm_g + (k - 4) * 25;
                #pragma unroll
                for (int j = 0; j < 5; ++j) {
                    int g = w16 + 16 * j;
                    if (g < 68) {
                        int vw = g / 17, v = g - vw * 17;
                        float vals[5];
                        #pragma unroll
                        for (int t2 = 0; t2 < 5; ++t2)
                            vals[t2] = bf2f(z1g[o * RS1 + vw * 120 + t2 * 24 + v]);
                        #pragma unroll
                        for (int tp = 0; tp < 5; ++tp) {
                            float y = b1v;
                            #pragma unroll
                            for (int t2 = 0; t2 < 5; ++t2)
                                y = fmaf(Ar[tp * 5 + t2], vals[t2], y);
                            z2s[(o >> 3) * SL8 + ((vw * 5 + tp) * 24 + v) * 8 + (o & 7)] =
                                f2bf(fmaxf(y, 0.f));
                        }
                    }
                }
            } else {   // View-mix (K=4), per-group VALU
                const float b1v = b1[lk * 16 + o];
                #pragma unroll
                for (int j = 0; j < 6; ++j) {
                    int g = w16 + 16 * j;
                    if (g < 85) {
                        int tt = g / 17, v = g - tt * 17;
                        float vals[4];
                        #pragma unroll
                        for (int vw = 0; vw < 4; ++vw)
                            vals[vw] = bf2f(z1g[o * RS1 + vw * 120 + tt * 24 + v]);
                        #pragma unroll
                        for (int vp = 0; vp < 4; ++vp) {
                            float y = b1v;
                            #pragma unroll
                            for (int vw = 0; vw < 4; ++vw)
                                y = fmaf(Avw_g[vp * 4 + vw], vals[vw], y);
                            z2s[(o >> 3) * SL8 + ((vp * 5 + tt) * 24 + v) * 8 + (o & 7)] =
                                f2bf(fmaxf(y, 0.f));
                        }
                    }
                }
            }
            __syncthreads();

            // ---- conv2 (transposed): acc[t] holds 4 channels of node tile*16+o ----
            #pragma unroll
            for (int t = 0; t < 8; ++t) {
                int tile = t * 4 + wv;
                if (tile < NTILE) {
                    int node = tile * 16 + o;
                    bf16x8 za = *(const bf16x8*)&z2s[(quad & 1) * SL8 + node * 8];
                    acc[t] = __builtin_amdgcn_mfma_f32_16x16x32_bf16(wt, za, acc[t], 0, 0, 0);
                }
            }
            // no barrier: next conv1 writes z1g only; barrier after it orders z2s reuse
        }

        // ---- finalize layer ----
        float4 Sb4 = *(const float4*)&SbA[l * 16 + quad * 4];
        if (l < 2) {
            #pragma unroll
            for (int t = 0; t < 8; ++t) {
                int tile = t * 4 + wv;
                if (tile < NTILE) {
                    f32x4 v;
                    v[0] = fmaxf(acc[t][0] + Sb4.x, 0.f);
                    v[1] = fmaxf(acc[t][1] + Sb4.y, 0.f);
                    v[2] = fmaxf(acc[t][2] + Sb4.z, 0.f);
                    v[3] = fmaxf(acc[t][3] + Sb4.w, 0.f);
                    res8[t] = v;
                    int s = tile * 16 + o;
                    *(uint2*)&xsb[(quad >> 1) * SLX + s * 8 + (quad & 1) * 4] =
                        make_uint2(pkbf2(v[0], v[1]), pkbf2(v[2], v[3]));
                }
            }
            __syncthreads();
        } else {
            #pragma unroll
            for (int t = 0; t < 8; ++t) {
                int tile = t * 4 + wv;
                if (tile < NTILE) {
                    int s = tile * 16 + o;
                    int m = s / 24, vv = s - m * 24;
                    if (vv < 17) {
                        int p = m * 17 + vv;
                        float* ob = out + ((size_t)((n * NODESV + p) * 16 + quad * 4)) * 256 + hw;
                        ob[0]   = fmaxf(acc[t][0] + Sb4.x, 0.f);
                        ob[256] = fmaxf(acc[t][1] + Sb4.y, 0.f);
                        ob[512] = fmaxf(acc[t][2] + Sb4.z, 0.f);
                        ob[768] = fmaxf(acc[t][3] + Sb4.w, 0.f);
                    }
                }
            }
        }
    }
}

extern "C" void kernel_launch(void* const* d_in, const int* in_sizes, int n_in,
                              void* d_out, int out_size, void* d_ws, size_t ws_size,
                              hipStream_t stream) {
    const float* x    = (const float*)d_in[0];
    const float* Asp  = (const float*)d_in[1];
    const float* Atm  = (const float*)d_in[2];
    const float* Avw  = (const float*)d_in[3];
    const float* Wg0  = (const float*)d_in[4];
    const float* bg0  = (const float*)d_in[5];
    const float* Wgx  = (const float*)d_in[6];
    const float* bgx  = (const float*)d_in[7];
    const float* g1   = (const float*)d_in[8];
    const float* b1   = (const float*)d_in[9];
    const float* Wt   = (const float*)d_in[10];
    const float* bt   = (const float*)d_in[11];
    const float* g2   = (const float*)d_in[12];
    const float* b2   = (const float*)d_in[13];
    float* out = (float*)d_out;

    stgcn_prep<<<dim3(21), dim3(64), 0, stream>>>(
        Wg0, bg0, Wgx, bgx, g1, b1, Wt, bt, g2, b2, d_ws);
    stgcn_main<<<dim3(8 * 256), dim3(256), 0, stream>>>(
        x, Asp, Atm, Avw, b1, d_ws, out);
}